// Round 11
// baseline (25310.054 us; speedup 1.0000x reference)
//
#include <hip/hip_runtime.h>
#include <hip/hip_fp16.h>

#define EPSF 1e-8f
#define SCOPE_AGT __HIP_MEMORY_SCOPE_AGENT

// T=512 B=64 IN=256 OUT=256 H=512 N=2048 C=64 R=4
// 128 blocks x 1024 threads (cooperative), 4 blocks per BATCH-PAIR: each block
// handles TWO batches (b0,b0+1) with the same chunk -> every W2h uint4 is
// loaded once from L2 and used for two input vectors (L2 stream halved vs R10).
// GEMV/projections via v_dot2_f32_f16 on fp16 LDS inputs (R5-proven).
// Exchange fabric/barriers identical to R4/R10 (proven): per-pair monotone
// counters, small-payload relaxed agent atomics, deferred rank-1 update.

typedef _Float16 h2_t __attribute__((ext_vector_type(2)));

struct P11 {
  const unsigned* W2h;   // [4 chunk][416 rp][512 cc] u32 = half2{row 2rp,2rp+1}
  const unsigned* Wkg2;  // [256 rp][128 cl] u32 half2 rowpair-packed (key64|gen64)
  const unsigned* Wy2;   // [256 rp][256 col] u32 half2 rowpair-packed
  const float* b_lstm;   // 2048
  const float* b_out;    // 256
  const float* b_key;    // 64
  const float* W_beta;   // 512
  const float* b_beta;   // 1
  const float* b_gen;    // 64
  const float* xs;       // [512][64][256]
  float* hbuf;           // [64 b][512]
  float* keyP;           // [64 b][4][64]
  float* genP;           // [64 b][4][64]
  float* yP;             // [64 b][4][256]
  float* betaP;          // [64 b][4]
  float* AccP;           // [64 b][4][64]
  float* ZP;             // [64 b][4]
  float* S2P;            // [64 b][4]
  unsigned* ctr;         // [32 bp][32]
  float* out;            // [512][64][256] + loss at 8388608
};

__device__ __forceinline__ float sigm(float x) { return 1.f / (1.f + __expf(-x)); }
__device__ __forceinline__ float aload(const float* p) {
  return __hip_atomic_load(p, __ATOMIC_RELAXED, SCOPE_AGT);
}
__device__ __forceinline__ void astore(float* p, float v) {
  __hip_atomic_store(p, v, __ATOMIC_RELAXED, SCOPE_AGT);
}
__device__ __forceinline__ h2_t u2h(unsigned u) {
  union { unsigned u; h2_t h; } x; x.u = u; return x.h;
}

#if defined(__has_builtin)
#if __has_builtin(__builtin_amdgcn_fdot2)
#define HAVE_FDOT2 1
#endif
#endif

__device__ __forceinline__ float dot2acc(h2_t a, h2_t b, float c) {
#ifdef HAVE_FDOT2
  return __builtin_amdgcn_fdot2(a, b, c, false);
#else
  return fmaf((float)a.x, (float)b.x, fmaf((float)a.y, (float)b.y, c));
#endif
}

__global__ void __launch_bounds__(1024, 4) dnc_b11(P11 P) {
  const int tid   = threadIdx.x;
  const int bid   = blockIdx.x;
  const int chunk = (bid >> 1) & 3;                 // == (bid&7)>>1 : one chunk per XCD
  const int bp    = ((bid >> 3) << 1) | (bid & 1);  // batch pair 0..31
  const int b0    = bp * 2;
  const int lane  = tid & 63;
  const int wv    = tid >> 6;
  const int sgrp  = lane >> 4;
  const int c4    = lane & 15;

  __shared__ _Float16 s_ih[2][832];   // per batch: [x(256)|h(512)|r(64)] fp16
  __shared__ float s_gates[2][512];
  __shared__ float s_c[2][128];
  __shared__ float s_part[8192];      // 32KB scratch (GEMV partials / proj / acc)
  __shared__ float s_e[2][512];
  __shared__ float s_den[2][512];     // per-slot norms (saves 16 VGPR)
  __shared__ float s_key[2][64], s_kprev[2][64], s_genv[2][64];
  __shared__ float s_wrZA[16], s_wrSA[16], s_wrZB[16], s_wrSB[16];
  __shared__ float s_bred[2][2];
  __shared__ float s_scal[2][4];      // per batch: 0:invZ_prev 1:S2_prev 2:beta 3:||key||

  unsigned* ctr = P.ctr + bp * 32;

  float4 mreg[2][8];                  // 2 batches x 512 own slots (64 VGPR)
#pragma unroll
  for (int bb = 0; bb < 2; ++bb)
#pragma unroll
    for (int i = 0; i < 8; ++i) mreg[bb][i] = make_float4(0.f, 0.f, 0.f, 0.f);

  for (int i = tid; i < 2 * 832; i += 1024) ((_Float16*)s_ih)[i] = (_Float16)0.f;
  if (tid < 512) { s_e[0][tid] = 0.f; s_e[1][tid] = 0.f; }
  if (tid < 128) { s_c[0][tid] = 0.f; s_c[1][tid] = 0.f; s_kprev[tid >> 6][tid & 63] = 0.f; }
  if (tid < 8) s_scal[tid >> 2][tid & 3] = 0.f;
  float lossacc = 0.f;
  __syncthreads();

  const int q  = tid >> 7;            // 0..7 rowpair-group
  const int cg = tid & 127;           // 4 gate-cols
  const unsigned* wbase = P.W2h + (size_t)chunk * 212992 + (cg << 2);

  for (int t = 0; t < 512; ++t) {
    // ---- load x_t for both batches (fp16)
    if (tid < 256) {
      const int bb = tid >> 7, i = tid & 127;
      const float2 xv = ((const float2*)P.xs)[((size_t)t * 64 + b0 + bb) * 128 + i];
      h2_t hv; hv.x = (_Float16)xv.x; hv.y = (_Float16)xv.y;
      *(h2_t*)&s_ih[bb][i * 2] = hv;
    }
    __syncthreads();

    // ---- GEMV part 1: rowpairs [q*48,+48) (x+h rows), shared weight load
    float4 accA = make_float4(0.f, 0.f, 0.f, 0.f);
    float4 accB = make_float4(0.f, 0.f, 0.f, 0.f);
    {
      const unsigned* wp = wbase + (size_t)(q * 48) * 512;
      const _Float16* iA = &s_ih[0][q * 96];
      const _Float16* iB = &s_ih[1][q * 96];
#pragma unroll 4
      for (int r = 0; r < 48; ++r) {
        const uint4 w = *(const uint4*)(wp + (size_t)r * 512);
        const h2_t vA = *(const h2_t*)(iA + r * 2);
        const h2_t vB = *(const h2_t*)(iB + r * 2);
        accA.x = dot2acc(u2h(w.x), vA, accA.x); accB.x = dot2acc(u2h(w.x), vB, accB.x);
        accA.y = dot2acc(u2h(w.y), vA, accA.y); accB.y = dot2acc(u2h(w.y), vB, accB.y);
        accA.z = dot2acc(u2h(w.z), vA, accA.z); accB.z = dot2acc(u2h(w.z), vB, accB.z);
        accA.w = dot2acc(u2h(w.w), vA, accA.w); accB.w = dot2acc(u2h(w.w), vB, accB.w);
      }
    }

    // ---- C: wait barrier B_{t-1}; finalize r_{t-1} for both batches
    if (t > 0) {
      if (tid == 0) {
        while (__hip_atomic_load(ctr, __ATOMIC_RELAXED, SCOPE_AGT) < 8u * (unsigned)t)
          __builtin_amdgcn_s_sleep(1);
      }
      __syncthreads();
      float a0 = 0.f, a1 = 0.f, a2 = 0.f, a3 = 0.f;
      if (tid < 128) {
        const int bb = tid >> 6, c = tid & 63;
        const float* ap = P.AccP + (b0 + bb) * 256 + c;
        a0 = aload(ap); a1 = aload(ap + 64); a2 = aload(ap + 128); a3 = aload(ap + 192);
      } else if (tid < 130) {
        const int bb = tid - 128;
        const float* zp = P.ZP + (b0 + bb) * 4;
        const float* sp = P.S2P + (b0 + bb) * 4;
        const float Z  = aload(zp) + aload(zp + 1) + aload(zp + 2) + aload(zp + 3);
        const float S2 = aload(sp) + aload(sp + 1) + aload(sp + 2) + aload(sp + 3);
        s_scal[bb][0] = 1.f / Z;  s_scal[bb][1] = S2;
      }
      __syncthreads();
      if (tid < 128) {
        const int bb = tid >> 6, c = tid & 63;
        const float iZ = s_scal[bb][0];
        const float r = iZ * ((a0 + a1 + a2 + a3) + s_scal[bb][1] * iZ * s_kprev[bb][c]);
        s_ih[bb][768 + c] = (_Float16)r;
      }
      __syncthreads();
    } else {
      __syncthreads();   // r pre-zeroed, scal pre-zeroed
    }

    // ---- GEMV part 2: r rows, rowpairs [384+q*4,+4)
    {
      const unsigned* wp = wbase + (size_t)(384 + q * 4) * 512;
      const _Float16* iA = &s_ih[0][768 + q * 8];
      const _Float16* iB = &s_ih[1][768 + q * 8];
#pragma unroll
      for (int r = 0; r < 4; ++r) {
        const uint4 w = *(const uint4*)(wp + (size_t)r * 512);
        const h2_t vA = *(const h2_t*)(iA + r * 2);
        const h2_t vB = *(const h2_t*)(iB + r * 2);
        accA.x = dot2acc(u2h(w.x), vA, accA.x); accB.x = dot2acc(u2h(w.x), vB, accB.x);
        accA.y = dot2acc(u2h(w.y), vA, accA.y); accB.y = dot2acc(u2h(w.y), vB, accB.y);
        accA.z = dot2acc(u2h(w.z), vA, accA.z); accB.z = dot2acc(u2h(w.z), vB, accB.z);
        accA.w = dot2acc(u2h(w.w), vA, accA.w); accB.w = dot2acc(u2h(w.w), vB, accB.w);
      }
    }
    *(float4*)&s_part[(q << 9) + (cg << 2)]        = accA;
    *(float4*)&s_part[4096 + (q << 9) + (cg << 2)] = accB;
    __syncthreads();

    // ---- gates reduce (A: tid<512, B: tid>=512)
    {
      const int bb = tid >> 9, col = tid & 511, off = bb * 4096;
      float g = 0.f;
#pragma unroll
      for (int k = 0; k < 8; ++k) g += s_part[off + (k << 9) + col];
      s_gates[bb][col] = g;
    }
    __syncthreads();

    // ---- LSTM -> h_t (own 128 j x 2 batches), publish h
    if (tid < 256) {
      const int bb = tid >> 7, jl = tid & 127, cb = chunk * 128 + jl;
      const float gi = s_gates[bb][jl * 4 + 0] + P.b_lstm[cb];
      const float gf = s_gates[bb][jl * 4 + 1] + P.b_lstm[512 + cb];
      const float gg = s_gates[bb][jl * 4 + 2] + P.b_lstm[1024 + cb];
      const float go = s_gates[bb][jl * 4 + 3] + P.b_lstm[1536 + cb];
      const float cn = sigm(gf) * s_c[bb][jl] + sigm(gi) * tanhf(gg);
      s_c[bb][jl] = cn;
      const float hn = sigm(go) * tanhf(cn);
      s_ih[bb][256 + cb] = (_Float16)hn;
      astore(P.hbuf + (b0 + bb) * 512 + cb, hn);
    }
    __syncthreads();

    // ---- E2: own-h-row projection partials (dot2, rowpair-packed weights)
    {
      {  // key|gen: isg(key/gen) x 8 rowgroups x 64 cols, 8 rowpairs each
        const int isg = tid >> 9, rg = (tid >> 6) & 7, c = tid & 63;
#pragma unroll
        for (int bb = 0; bb < 2; ++bb) {
          float a = 0.f;
#pragma unroll
          for (int k = 0; k < 8; ++k) {
            const unsigned w = P.Wkg2[(size_t)(chunk * 64 + rg * 8 + k) * 128 + isg * 64 + c];
            const h2_t v = *(const h2_t*)&s_ih[bb][256 + chunk * 128 + rg * 16 + 2 * k];
            a = dot2acc(u2h(w), v, a);
          }
          s_part[bb * 2048 + rg * 128 + isg * 64 + c] = a;
        }
      }
      {  // y: 4 rowgroups x 256 cols, 16 rowpairs each
        const int rg = tid >> 8, col = tid & 255;
#pragma unroll
        for (int bb = 0; bb < 2; ++bb) {
          float a = 0.f;
#pragma unroll
          for (int k = 0; k < 16; ++k) {
            const unsigned w = P.Wy2[(size_t)(chunk * 64 + rg * 16 + k) * 256 + col];
            const h2_t v = *(const h2_t*)&s_ih[bb][256 + chunk * 128 + rg * 32 + 2 * k];
            a = dot2acc(u2h(w), v, a);
          }
          s_part[bb * 2048 + 1024 + (rg << 8) + col] = a;
        }
      }
      {  // beta partials: waves 0,1 (A), 8,9 (B) over own 128 rows
        if (tid < 128 || (tid >= 512 && tid < 640)) {
          const int bb = tid >> 9, i = tid & 127;
          const float hv = (float)s_ih[bb][256 + chunk * 128 + i];
          float pb = hv * P.W_beta[chunk * 128 + i];
#pragma unroll
          for (int off = 32; off; off >>= 1) pb += __shfl_down(pb, off);
          if (lane == 0) s_bred[bb][wv & 1] = pb;
        }
      }
    }
    __syncthreads();
    // ---- E3: reduce + publish partials (both batches)
    {
      const int bb = tid >> 9, t2 = tid & 511, off = bb * 2048;
      if (t2 < 64) {
        float v = 0.f;
#pragma unroll
        for (int k = 0; k < 8; ++k) v += s_part[off + k * 128 + t2];
        astore(P.keyP + ((b0 + bb) * 4 + chunk) * 64 + t2, v);
      } else if (t2 < 128) {
        const int c = t2 - 64;
        float v = 0.f;
#pragma unroll
        for (int k = 0; k < 8; ++k) v += s_part[off + k * 128 + 64 + c];
        astore(P.genP + ((b0 + bb) * 4 + chunk) * 64 + c, v);
      } else if (t2 < 384) {
        const int col = t2 - 128;
        astore(P.yP + ((b0 + bb) * 4 + chunk) * 256 + col,
               s_part[off + 1024 + col] + s_part[off + 1280 + col]
             + s_part[off + 1536 + col] + s_part[off + 1792 + col]);
      } else if (t2 == 384) {
        astore(P.betaP + (b0 + bb) * 4 + chunk, s_bred[bb][0] + s_bred[bb][1]);
      }
    }
    __syncthreads();                              // drains stores before post
    if (tid == 0) __hip_atomic_fetch_add(ctr, 1u, __ATOMIC_RELEASE, SCOPE_AGT);  // post A

    // ---- G1 (A-barrier shadow): pending rank-1 update + slot norms (both batches)
    {
      const int nbase = (wv * 4 + sgrp) * 8;
#pragma unroll
      for (int bb = 0; bb < 2; ++bb) {
        const float invZp = s_scal[bb][0];
        const float4 kp4 = ((const float4*)s_kprev[bb])[c4];
#pragma unroll
        for (int it = 0; it < 8; ++it) {
          float4 m4 = mreg[bb][it];
          const float wpv = s_e[bb][nbase + it] * invZp;   // w_{t-1}[n] (0 at t=0)
          m4.x = fmaf(wpv, kp4.x, m4.x); m4.y = fmaf(wpv, kp4.y, m4.y);
          m4.z = fmaf(wpv, kp4.z, m4.z); m4.w = fmaf(wpv, kp4.w, m4.w);
          float ssq = m4.x * m4.x + m4.y * m4.y + m4.z * m4.z + m4.w * m4.w;
#pragma unroll
          for (int off = 1; off < 16; off <<= 1) ssq += __shfl_xor(ssq, off);
          if (c4 == 0) s_den[bb][nbase + it] = fmaxf(sqrtf(ssq), EPSF);
          mreg[bb][it] = m4;
        }
      }
    }

    // ---- F: wait A; peers' h; assemble key/gen/y/beta (both batches)
    if (tid == 0) {
      while (__hip_atomic_load(ctr, __ATOMIC_RELAXED, SCOPE_AGT) < 8u * (unsigned)t + 4u)
        __builtin_amdgcn_s_sleep(1);
    }
    __syncthreads();
    if (tid < 768) {
      const int bb = (tid >= 384) ? 1 : 0;
      const int i = tid - bb * 384;
      const int pc = i >> 7;
      const int pcc = pc + (pc >= chunk ? 1 : 0);
      const int jl = i & 127;
      const float hv = aload(P.hbuf + (b0 + bb) * 512 + pcc * 128 + jl);
      s_ih[bb][256 + pcc * 128 + jl] = (_Float16)hv;
    }
    {
      const int bb = tid >> 8;                    // role2: A uses tid<256, B uses [256,512)
      const int t2 = tid & 255;
      if (tid < 512) {
        if (t2 < 64) {
          const float* kp = P.keyP + (b0 + bb) * 256 + t2;
          s_key[bb][t2] = aload(kp) + aload(kp + 64) + aload(kp + 128) + aload(kp + 192) + P.b_key[t2];
        } else if (t2 < 128) {
          const int c = t2 - 64;
          const float* gp = P.genP + (b0 + bb) * 256 + c;
          s_genv[bb][c] = aload(gp) + aload(gp + 64) + aload(gp + 128) + aload(gp + 192) + P.b_gen[c];
        } else if (t2 < 192) {
          const int col = t2 - 128, oc = chunk * 64 + col;
          const float* yp = P.yP + (b0 + bb) * 1024 + oc;
          P.out[((size_t)t * 64 + b0 + bb) * 256 + oc] =
              aload(yp) + aload(yp + 256) + aload(yp + 512) + aload(yp + 768) + P.b_out[oc];
        } else if (t2 == 192) {
          const float* bpt = P.betaP + (b0 + bb) * 4;
          const float s = aload(bpt) + aload(bpt + 1) + aload(bpt + 2) + aload(bpt + 3) + P.b_beta[0];
          s_scal[bb][2] = (s > 20.f) ? s : log1pf(__expf(s));   // softplus
        }
      }
    }
    __syncthreads();
    if (wv < 2) {                                 // ||key|| per batch
      const float kv = s_key[wv][lane];
      float sq = kv * kv;
#pragma unroll
      for (int off = 32; off; off >>= 1) sq += __shfl_down(sq, off);
      if (lane == 0) s_scal[wv][3] = fmaxf(sqrtf(sq), EPSF);
    } else if ((wv == 2 || wv == 3) && chunk == 0) {   // loss per batch
      const int bb = wv - 2;
      const float d = s_key[bb][lane] - s_genv[bb][lane];
      float ds = d * d;
#pragma unroll
      for (int off = 32; off; off >>= 1) ds += __shfl_down(ds, off);
      if (lane == 0) lossacc += ds;               // held by tid 128 (A), 192 (B)
    }
    __syncthreads();

    // ---- G2: sim/exp/acc on updated register mem (both batches)
    {
      const int nbase = (wv * 4 + sgrp) * 8;
      const float betaA = s_scal[0][2], knA = s_scal[0][3];
      const float betaB = s_scal[1][2], knB = s_scal[1][3];
      const float4 kkA = ((const float4*)s_key[0])[c4];
      const float4 kkB = ((const float4*)s_key[1])[c4];
      float ZpA = 0.f, S2pA = 0.f, ZpB = 0.f, S2pB = 0.f;
      float4 acA = make_float4(0.f, 0.f, 0.f, 0.f);
      float4 acB = make_float4(0.f, 0.f, 0.f, 0.f);
#pragma unroll
      for (int it = 0; it < 8; ++it) {
        {
          const float4 m4 = mreg[0][it];
          float num = m4.x * kkA.x + m4.y * kkA.y + m4.z * kkA.z + m4.w * kkA.w;
#pragma unroll
          for (int off = 1; off < 16; off <<= 1) num += __shfl_xor(num, off);
          const float e = __expf(betaA * (num / (s_den[0][nbase + it] * knA)));
          if (c4 == 0) { s_e[0][nbase + it] = e; ZpA += e; S2pA += e * e; }
          acA.x = fmaf(e, m4.x, acA.x); acA.y = fmaf(e, m4.y, acA.y);
          acA.z = fmaf(e, m4.z, acA.z); acA.w = fmaf(e, m4.w, acA.w);
        }
        {
          const float4 m4 = mreg[1][it];
          float num = m4.x * kkB.x + m4.y * kkB.y + m4.z * kkB.z + m4.w * kkB.w;
#pragma unroll
          for (int off = 1; off < 16; off <<= 1) num += __shfl_xor(num, off);
          const float e = __expf(betaB * (num / (s_den[1][nbase + it] * knB)));
          if (c4 == 0) { s_e[1][nbase + it] = e; ZpB += e; S2pB += e * e; }
          acB.x = fmaf(e, m4.x, acB.x); acB.y = fmaf(e, m4.y, acB.y);
          acB.z = fmaf(e, m4.z, acB.z); acB.w = fmaf(e, m4.w, acB.w);
        }
      }
#pragma unroll
      for (int off = 32; off; off >>= 1) {
        ZpA += __shfl_down(ZpA, off); S2pA += __shfl_down(S2pA, off);
        ZpB += __shfl_down(ZpB, off); S2pB += __shfl_down(S2pB, off);
      }
      if (lane == 0) { s_wrZA[wv] = ZpA; s_wrSA[wv] = S2pA; s_wrZB[wv] = ZpB; s_wrSB[wv] = S2pB; }
#pragma unroll
      for (int off = 16; off < 64; off <<= 1) {
        acA.x += __shfl_down(acA.x, off); acA.y += __shfl_down(acA.y, off);
        acA.z += __shfl_down(acA.z, off); acA.w += __shfl_down(acA.w, off);
        acB.x += __shfl_down(acB.x, off); acB.y += __shfl_down(acB.y, off);
        acB.z += __shfl_down(acB.z, off); acB.w += __shfl_down(acB.w, off);
      }
      if (lane < 16) {
        ((float4*)s_part)[wv * 16 + lane]       = acA;
        ((float4*)s_part)[256 + wv * 16 + lane] = acB;
      }
    }
    __syncthreads();
    // ---- publish Acc/Z/S2 + kprev (both batches)
    if (tid < 64) {
      float a = 0.f;
#pragma unroll
      for (int w = 0; w < 16; ++w) a += s_part[w * 64 + tid];
      astore(P.AccP + (b0 * 4 + chunk) * 64 + tid, a);
      s_kprev[0][tid] = s_key[0][tid];
    } else if (tid == 64) {
      float Z = 0.f, S2 = 0.f;
#pragma unroll
      for (int k = 0; k < 16; ++k) { Z += s_wrZA[k]; S2 += s_wrSA[k]; }
      astore(P.ZP + b0 * 4 + chunk, Z);
      astore(P.S2P + b0 * 4 + chunk, S2);
    } else if (tid >= 128 && tid < 192) {
      const int c = tid - 128;
      float a = 0.f;
#pragma unroll
      for (int w = 0; w < 16; ++w) a += s_part[1024 + w * 64 + c];
      astore(P.AccP + ((b0 + 1) * 4 + chunk) * 64 + c, a);
      s_kprev[1][c] = s_key[1][c];
    } else if (tid == 192) {
      float Z = 0.f, S2 = 0.f;
#pragma unroll
      for (int k = 0; k < 16; ++k) { Z += s_wrZB[k]; S2 += s_wrSB[k]; }
      astore(P.ZP + (b0 + 1) * 4 + chunk, Z);
      astore(P.S2P + (b0 + 1) * 4 + chunk, S2);
    }
    __syncthreads();                              // drains stores before post
    if (tid == 0) __hip_atomic_fetch_add(ctr, 1u, __ATOMIC_RELEASE, SCOPE_AGT);  // post B
  }

  if (chunk == 0 && (tid == 128 || tid == 192))
    atomicAdd(P.out + 8388608, lossacc * (1.f / 4096.f));
}

//============================ prep kernels ============================
// W2h[chunk][rp][cc] = half2{W[2rp][col], W[2rp+1][col]}, col = g*512+chunk*128+jl,
// cc = jl*4+g. rows [0,256)=W_ih(x), [256,768)=W_hh, [768,832)=W_ih read-rows folded (R=4).
__global__ void build_w2h(const float* __restrict__ W_ih, const float* __restrict__ W_hh,
                          unsigned* __restrict__ W2h) {
  const int id = blockIdx.x * 256 + threadIdx.x;   // over 4*416*512
  if (id >= 851968) return;
  const int chunk = id / 212992;
  const int rem   = id % 212992;
  const int rp    = rem >> 9;
  const int cc    = rem & 511;
  const int jl = cc >> 2, g = cc & 3;
  const int col = g * 512 + chunk * 128 + jl;
  float v[2];
#pragma unroll
  for (int k = 0; k < 2; ++k) {
    const int row = rp * 2 + k;
    if (row < 256)      v[k] = W_ih[(size_t)row * 2048 + col];
    else if (row < 768) v[k] = W_hh[(size_t)(row - 256) * 2048 + col];
    else {
      const float* p0 = W_ih + (size_t)(256 + (row - 768) * 4) * 2048 + col;
      v[k] = p0[0] + p0[2048] + p0[4096] + p0[6144];
    }
  }
  const __half2 h2v = __floats2half2_rn(v[0], v[1]);
  W2h[id] = *(const unsigned*)&h2v;
}

// Wkg2[rp][cl]: rowpair-packed key|gen weights.
__global__ void build_wkg2(const float* __restrict__ W_key, const float* __restrict__ W_gen,
                           unsigned* __restrict__ Wkg2) {
  const int id = blockIdx.x * 256 + threadIdx.x;   // 256*128
  if (id >= 32768) return;
  const int rp = id >> 7, cl = id & 127;
  float v[2];
#pragma unroll
  for (int k = 0; k < 2; ++k) {
    const int row = rp * 2 + k;
    v[k] = (cl < 64) ? W_key[(size_t)row * 64 + cl] : W_gen[(size_t)row * 64 + cl - 64];
  }
  const __half2 h2v = __floats2half2_rn(v[0], v[1]);
  Wkg2[id] = *(const unsigned*)&h2v;
}

// Wy2[rp][col]: rowpair-packed W_out.
__global__ void build_wy2(const float* __restrict__ W_out, unsigned* __restrict__ Wy2) {
  const int id = blockIdx.x * 256 + threadIdx.x;   // 256*256
  if (id >= 65536) return;
  const int rp = id >> 8, col = id & 255;
  const __half2 h2v = __floats2half2_rn(W_out[(size_t)(rp * 2) * 256 + col],
                                        W_out[(size_t)(rp * 2 + 1) * 256 + col]);
  Wy2[id] = *(const unsigned*)&h2v;
}

extern "C" void kernel_launch(void* const* d_in, const int* in_sizes, int n_in,
                              void* d_out, int out_size, void* d_ws, size_t ws_size,
                              hipStream_t stream) {
  const float* xs     = (const float*)d_in[0];
  const float* W_ih   = (const float*)d_in[1];
  const float* W_hh   = (const float*)d_in[2];
  const float* b_lstm = (const float*)d_in[3];
  const float* W_out  = (const float*)d_in[4];
  const float* b_out  = (const float*)d_in[5];
  const float* W_key  = (const float*)d_in[6];
  const float* b_key  = (const float*)d_in[7];
  const float* W_beta = (const float*)d_in[8];
  const float* b_beta = (const float*)d_in[9];
  const float* W_gen  = (const float*)d_in[10];
  const float* b_gen  = (const float*)d_in[11];
  float* out = (float*)d_out;

  float* ws = (float*)d_ws;
  unsigned* W2h  = (unsigned*)ws;                 //   851,968 u32
  unsigned* Wkg2 = (unsigned*)(ws + 851968);      //    32,768 u32
  unsigned* Wy2  = (unsigned*)(ws + 884736);      //    65,536 u32
  float* hbuf  = ws     + 950272;                 //    32,768
  float* keyP  = hbuf   + 32768;                  //    16,384
  float* genP  = keyP   + 16384;                  //    16,384
  float* yP    = genP   + 16384;                  //    65,536
  float* betaP = yP     + 65536;                  //       256
  float* AccP  = betaP  + 256;                    //    16,384
  float* ZP    = AccP   + 16384;                  //       256
  float* S2P   = ZP     + 256;                    //       256
  unsigned* ctr = (unsigned*)(S2P + 256);         //     1,024 u32

  hipMemsetAsync(ctr, 0, 1024 * sizeof(unsigned), stream);
  hipMemsetAsync(out + 8388608, 0, sizeof(float), stream);

  build_w2h<<<dim3(3328), dim3(256), 0, stream>>>(W_ih, W_hh, W2h);
  build_wkg2<<<dim3(128), dim3(256), 0, stream>>>(W_key, W_gen, Wkg2);
  build_wy2<<<dim3(256),  dim3(256), 0, stream>>>(W_out, Wy2);

  P11 prm;
  prm.W2h = W2h; prm.Wkg2 = Wkg2; prm.Wy2 = Wy2;
  prm.b_lstm = b_lstm; prm.b_out = b_out; prm.b_key = b_key;
  prm.W_beta = W_beta; prm.b_beta = b_beta; prm.b_gen = b_gen;
  prm.xs = xs;
  prm.hbuf = hbuf; prm.keyP = keyP; prm.genP = genP; prm.yP = yP; prm.betaP = betaP;
  prm.AccP = AccP; prm.ZP = ZP; prm.S2P = S2P;
  prm.ctr = ctr;  prm.out = out;

  void* kargs[] = { &prm };
  hipLaunchCooperativeKernel(reinterpret_cast<void*>(&dnc_b11),
                             dim3(128), dim3(1024), kargs, 0, stream);
}

// Round 13
// 14325.804 us; speedup vs baseline: 1.7667x; 1.7667x over previous
//
#include <hip/hip_runtime.h>
#include <hip/hip_fp16.h>

#define EPSF 1e-8f
#define SCOPE_AGT __HIP_MEMORY_SCOPE_AGENT

// T=512 B=64 IN=256 OUT=256 H=512 N=2048 C=64 R=4
// FINAL HARDENED (R10 structure + memory-model hardening after R12's
// intermittent post-timing divergence):
//  - acquire agent fences at both barrier waits (R3-proven): every cross-XCD
//    read is guaranteed fresh regardless of L2 allocation corner cases.
//  - parity (t&1) double-buffering of ALL exchange payloads: no cross-step
//    write-after-read window exists even in principle.
// 256 blocks x 1024 threads (1/CU, cooperative), 4 blocks/batch; mem register-
// resident (32 VGPR); deferred rank-1 update in the barrier shadow; fp16
// recurrent + projection weights with fp32 accumulate.

typedef _Float16 h2_t __attribute__((ext_vector_type(2)));

struct P4 {
  const unsigned* W2h;  // [4 chunk][416 rowpairs][512 cc] packed half2
  const _Float16* Wkg;  // [512 row][128 cl]  cl: key64|gen64
  const _Float16* Wy;   // [512 row][256 col]
  const float* b_lstm;  // 2048
  const float* b_out;   // 256
  const float* b_key;   // 64
  const float* W_beta;  // 512
  const float* b_beta;  // 1
  const float* b_gen;   // 64
  const float* xs;      // [512][64][256]
  float* hbuf;          // [2][64][512]
  float* keyP;          // [2][64][4][64]
  float* genP;          // [2][64][4][64]
  float* yP;            // [2][64][4][256]
  float* betaP;         // [2][64][4]
  float* AccP;          // [2][64][4][64]
  float* ZP;            // [2][64][4]
  float* S2P;           // [2][64][4]
  unsigned* ctr;        // [64][32]
  float* out;           // [512][64][256] + loss at 8388608
};

__device__ __forceinline__ float sigm(float x) { return 1.f / (1.f + __expf(-x)); }
__device__ __forceinline__ float aload(const float* p) {
  return __hip_atomic_load(p, __ATOMIC_RELAXED, SCOPE_AGT);
}
__device__ __forceinline__ void astore(float* p, float v) {
  __hip_atomic_store(p, v, __ATOMIC_RELAXED, SCOPE_AGT);
}

__global__ void __launch_bounds__(1024, 4) dnc_b4(P4 P) {
  const int tid   = threadIdx.x;
  const int bid   = blockIdx.x;
  const int chunk = (bid >> 1) & 3;                 // XCD(bid%8) hosts one chunk value
  const int b     = ((bid >> 3) << 1) | (bid & 1);
  const int lane  = tid & 63;
  const int wv    = tid >> 6;
  const int sgrp  = lane >> 4;
  const int c4    = lane & 15;

  __shared__ float s_inp[832];     // [x(256) | h(512) | r(64)]
  __shared__ float s_gates[512];
  __shared__ float s_c[128];
  __shared__ float s_part[4096];
  __shared__ float s_e[512];
  __shared__ float s_key[64], s_kprev[64], s_genv[64];
  __shared__ float s_wred[32];
  __shared__ float s_scal[4];      // 0:invZ_prev 1:S2_prev 2:beta 3:||key||

  unsigned* ctr = P.ctr + b * 32;

  float4 mreg[8];                  // own 512 slots
  float  sden[8];
#pragma unroll
  for (int i = 0; i < 8; ++i) mreg[i] = make_float4(0.f, 0.f, 0.f, 0.f);

  for (int i = 256 + tid; i < 832; i += 1024) s_inp[i] = 0.f;
  if (tid < 128) s_c[tid] = 0.f;
  if (tid < 512) s_e[tid] = 0.f;
  if (tid < 64)  s_kprev[tid] = 0.f;
  float lossacc = 0.f;
  __syncthreads();

  const int q  = tid >> 7;         // 0..7 rowpair-chunk
  const int cg = tid & 127;        // col-group (4 cols)
  const unsigned* wbase = P.W2h + (size_t)chunk * 212992 + (cg << 2);

  for (int t = 0; t < 512; ++t) {
    const int p = t & 1, pp = p ^ 1;

    // ---- load x_t
    if (tid < 128)
      ((float2*)s_inp)[tid] = ((const float2*)P.xs)[((size_t)t * 64 + b) * 128 + tid];
    __syncthreads();

    // ---- GEMV part 1: rowpairs [q*48,+48) (x+h rows; no barrier needed)
    float4 acc = make_float4(0.f, 0.f, 0.f, 0.f);
    {
      const unsigned* wp = wbase + (size_t)(q * 48) * 512;
      const float* ip = s_inp + q * 96;
#pragma unroll 4
      for (int r = 0; r < 48; ++r) {
        const uint4 w = *(const uint4*)(wp + (size_t)r * 512);
        const float2 v = *(const float2*)(ip + r * 2);
        const __half2* h2 = (const __half2*)&w;
        const float2 f0 = __half22float2(h2[0]), f1 = __half22float2(h2[1]);
        const float2 f2 = __half22float2(h2[2]), f3 = __half22float2(h2[3]);
        acc.x = fmaf(v.x, f0.x, fmaf(v.y, f0.y, acc.x));
        acc.y = fmaf(v.x, f1.x, fmaf(v.y, f1.y, acc.y));
        acc.z = fmaf(v.x, f2.x, fmaf(v.y, f2.y, acc.z));
        acc.w = fmaf(v.x, f3.x, fmaf(v.y, f3.y, acc.w));
      }
    }

    // ---- C: wait barrier B_{t-1} (acquire); finalize r_{t-1}
    if (t > 0) {
      if (tid == 0) {
        while (__hip_atomic_load(ctr, __ATOMIC_RELAXED, SCOPE_AGT) < 8u * (unsigned)t)
          __builtin_amdgcn_s_sleep(1);
        __builtin_amdgcn_fence(__ATOMIC_ACQUIRE, "agent");   // invalidate L1+L2
      }
      __syncthreads();
      float a0 = 0.f, a1 = 0.f, a2 = 0.f, a3 = 0.f;
      if (tid < 64) {
        const float* ap = P.AccP + pp * 16384 + b * 256 + tid;
        a0 = aload(ap); a1 = aload(ap + 64); a2 = aload(ap + 128); a3 = aload(ap + 192);
      } else if (tid == 64) {
        const float* zp = P.ZP + pp * 256 + b * 4;
        const float* sp = P.S2P + pp * 256 + b * 4;
        const float Z  = aload(zp) + aload(zp + 1) + aload(zp + 2) + aload(zp + 3);
        const float S2 = aload(sp) + aload(sp + 1) + aload(sp + 2) + aload(sp + 3);
        s_scal[0] = 1.f / Z;  s_scal[1] = S2;
      }
      __syncthreads();
      if (tid < 64) {
        const float iZ = s_scal[0];
        s_inp[768 + tid] = iZ * ((a0 + a1 + a2 + a3) + s_scal[1] * iZ * s_kprev[tid]);
      }
      __syncthreads();
    } else {
      if (tid == 64) { s_scal[0] = 0.f; s_scal[1] = 0.f; }  // r pre-zeroed
      __syncthreads();
    }

    // ---- GEMV part 2: rowpairs [384+q*4,+4) (r rows)
    {
      const unsigned* wp = wbase + (size_t)(384 + q * 4) * 512;
      const float* ip = s_inp + 768 + q * 8;
#pragma unroll
      for (int r = 0; r < 4; ++r) {
        const uint4 w = *(const uint4*)(wp + (size_t)r * 512);
        const float2 v = *(const float2*)(ip + r * 2);
        const __half2* h2 = (const __half2*)&w;
        const float2 f0 = __half22float2(h2[0]), f1 = __half22float2(h2[1]);
        const float2 f2 = __half22float2(h2[2]), f3 = __half22float2(h2[3]);
        acc.x = fmaf(v.x, f0.x, fmaf(v.y, f0.y, acc.x));
        acc.y = fmaf(v.x, f1.x, fmaf(v.y, f1.y, acc.y));
        acc.z = fmaf(v.x, f2.x, fmaf(v.y, f2.y, acc.z));
        acc.w = fmaf(v.x, f3.x, fmaf(v.y, f3.y, acc.w));
      }
    }
    *(float4*)&s_part[(q << 9) + (cg << 2)] = acc;
    __syncthreads();

    // ---- gates reduce + LSTM -> h_t (own 128 j), publish h chunk
    if (tid < 512) {
      s_gates[tid] = s_part[tid]        + s_part[512 + tid]  + s_part[1024 + tid] + s_part[1536 + tid]
                   + s_part[2048 + tid] + s_part[2560 + tid] + s_part[3072 + tid] + s_part[3584 + tid];
    }
    __syncthreads();
    if (tid < 128) {
      const int jl = tid, cb = chunk * 128 + jl;
      const float gi = s_gates[jl * 4 + 0] + P.b_lstm[cb];
      const float gf = s_gates[jl * 4 + 1] + P.b_lstm[512 + cb];
      const float gg = s_gates[jl * 4 + 2] + P.b_lstm[1024 + cb];
      const float go = s_gates[jl * 4 + 3] + P.b_lstm[1536 + cb];
      const float cn = sigm(gf) * s_c[jl] + sigm(gi) * tanhf(gg);
      s_c[jl] = cn;
      const float hn = sigm(go) * tanhf(cn);
      s_inp[256 + cb] = hn;
      astore(P.hbuf + p * 32768 + b * 512 + cb, hn);
    }
    __syncthreads();

    // ---- E2: own-h-row projection partials (rows [chunk*128,+128)), fp16 weights
    {
      const float* h = s_inp + 256 + chunk * 128;
      {  // keyP (tid<512) / genP (tid>=512): 8 rowgroups x 64 cols, 16 rows each
        const int isg = tid >> 9, rg = (tid >> 6) & 7, c = tid & 63;
        const _Float16* wp2 = P.Wkg + (size_t)(chunk * 128 + rg * 16) * 128 + isg * 64 + c;
        const float* hh = h + rg * 16;
        float a2 = 0.f;
#pragma unroll
        for (int r2 = 0; r2 < 16; ++r2) a2 = fmaf(hh[r2], (float)wp2[(size_t)r2 * 128], a2);
        s_part[tid] = a2;
      }
      {  // yP: 4 rowgroups x 256 cols, 32 rows each
        const int rg = tid >> 8, col = tid & 255;
        const _Float16* wp2 = P.Wy + (size_t)(chunk * 128 + rg * 32) * 256 + col;
        const float* hh = h + rg * 32;
        float a2 = 0.f;
#pragma unroll 8
        for (int r2 = 0; r2 < 32; ++r2) a2 = fmaf(hh[r2], (float)wp2[(size_t)r2 * 256], a2);
        s_part[1024 + (rg << 8) + col] = a2;
      }
      {  // betaP: own 128 rows (waves 0,1)
        float pb = (tid < 128) ? h[tid] * P.W_beta[chunk * 128 + tid] : 0.f;
#pragma unroll
        for (int off = 32; off; off >>= 1) pb += __shfl_down(pb, off);
        if (tid < 128 && lane == 0) s_wred[wv] = pb;
      }
    }
    __syncthreads();
    // ---- E3: reduce + publish partials (parity p)
    if (tid < 64) {
      float v = 0.f;
#pragma unroll
      for (int k = 0; k < 8; ++k) v += s_part[k * 64 + tid];
      astore(P.keyP + p * 16384 + (b * 4 + chunk) * 64 + tid, v);
    } else if (tid < 128) {
      const int c = tid - 64;
      float v = 0.f;
#pragma unroll
      for (int k = 0; k < 8; ++k) v += s_part[512 + k * 64 + c];
      astore(P.genP + p * 16384 + (b * 4 + chunk) * 64 + c, v);
    } else if (tid < 384) {
      const int col = tid - 128;
      astore(P.yP + p * 65536 + (b * 4 + chunk) * 256 + col,
             s_part[1024 + col] + s_part[1280 + col] + s_part[1536 + col] + s_part[1792 + col]);
    } else if (tid == 384) {
      astore(P.betaP + p * 256 + b * 4 + chunk, s_wred[0] + s_wred[1]);
    }
    __syncthreads();                              // drains stores (vmcnt) before post
    if (tid == 0) __hip_atomic_fetch_add(ctr, 1u, __ATOMIC_RELEASE, SCOPE_AGT);  // post A

    // ---- G1 (in barrier-A shadow): apply pending rank-1 update; slot norms
    {
      const float invZp = s_scal[0];
      const float4 kp4 = ((const float4*)s_kprev)[c4];
      const int nbase = (wv * 4 + sgrp) * 8;
#pragma unroll
      for (int it = 0; it < 8; ++it) {
        float4 m4 = mreg[it];
        const float wpv = s_e[nbase + it] * invZp;   // w_{t-1}[n]  (0 at t=0)
        m4.x = fmaf(wpv, kp4.x, m4.x); m4.y = fmaf(wpv, kp4.y, m4.y);
        m4.z = fmaf(wpv, kp4.z, m4.z); m4.w = fmaf(wpv, kp4.w, m4.w);
        float ssq = m4.x * m4.x + m4.y * m4.y + m4.z * m4.z + m4.w * m4.w;
#pragma unroll
        for (int off = 1; off < 16; off <<= 1) ssq += __shfl_xor(ssq, off);
        sden[it] = fmaxf(sqrtf(ssq), EPSF);
        mreg[it] = m4;
      }
    }

    // ---- F: wait A (acquire); assemble key/gen/y/beta; fetch peers' h
    if (tid == 0) {
      while (__hip_atomic_load(ctr, __ATOMIC_RELAXED, SCOPE_AGT) < 8u * (unsigned)t + 4u)
        __builtin_amdgcn_s_sleep(1);
      __builtin_amdgcn_fence(__ATOMIC_ACQUIRE, "agent");     // invalidate L1+L2
    }
    __syncthreads();
    if (tid < 64) {
      const float* kp = P.keyP + p * 16384 + b * 256 + tid;
      s_key[tid] = aload(kp) + aload(kp + 64) + aload(kp + 128) + aload(kp + 192) + P.b_key[tid];
    } else if (tid < 128) {
      const int c = tid - 64;
      const float* gp = P.genP + p * 16384 + b * 256 + c;
      s_genv[c] = aload(gp) + aload(gp + 64) + aload(gp + 128) + aload(gp + 192) + P.b_gen[c];
    } else if (tid < 192) {
      const int col = tid - 128, oc = chunk * 64 + col;
      const float* yp = P.yP + p * 65536 + b * 1024 + oc;
      P.out[((size_t)t * 64 + b) * 256 + oc] =
          aload(yp) + aload(yp + 256) + aload(yp + 512) + aload(yp + 768) + P.b_out[oc];
    } else if (tid == 192) {
      const float* bp = P.betaP + p * 256 + b * 4;
      const float s = aload(bp) + aload(bp + 1) + aload(bp + 2) + aload(bp + 3) + P.b_beta[0];
      s_scal[2] = (s > 20.f) ? s : log1pf(__expf(s));   // softplus
    } else if (tid >= 256 && tid < 640) {
      const int i = tid - 256;
      const int pc = i >> 7;
      const int pcc = pc + (pc >= chunk ? 1 : 0);       // peer chunks
      const int jl = i & 127;
      s_inp[256 + pcc * 128 + jl] = aload(P.hbuf + p * 32768 + b * 512 + pcc * 128 + jl);
    }
    __syncthreads();
    if (wv == 0) {
      const float kv = s_key[lane];
      float sq = kv * kv;
#pragma unroll
      for (int off = 32; off; off >>= 1) sq += __shfl_down(sq, off);
      if (lane == 0) s_scal[3] = fmaxf(sqrtf(sq), EPSF);
    } else if (wv == 1 && chunk == 0) {
      const float d = s_key[lane] - s_genv[lane];
      float ds = d * d;
#pragma unroll
      for (int off = 32; off; off >>= 1) ds += __shfl_down(ds, off);
      if (lane == 0) lossacc += ds;                      // tid 64
    }
    __syncthreads();

    // ---- G2: sim/exp/acc on updated mem (registers)
    {
      const float beta = s_scal[2], kn = s_scal[3];
      const float4 kk = ((const float4*)s_key)[c4];
      float Zp = 0.f, S2p = 0.f;
      float4 acc4 = make_float4(0.f, 0.f, 0.f, 0.f);
      const int nbase = (wv * 4 + sgrp) * 8;
#pragma unroll
      for (int it = 0; it < 8; ++it) {
        const float4 m4 = mreg[it];
        float num = m4.x * kk.x + m4.y * kk.y + m4.z * kk.z + m4.w * kk.w;
#pragma unroll
        for (int off = 1; off < 16; off <<= 1) num += __shfl_xor(num, off);
        const float e = __expf(beta * (num / (sden[it] * kn)));
        if (c4 == 0) { s_e[nbase + it] = e; Zp += e; S2p += e * e; }
        acc4.x = fmaf(e, m4.x, acc4.x); acc4.y = fmaf(e, m4.y, acc4.y);
        acc4.z = fmaf(e, m4.z, acc4.z); acc4.w = fmaf(e, m4.w, acc4.w);
      }
#pragma unroll
      for (int off = 32; off; off >>= 1) { Zp += __shfl_down(Zp, off); S2p += __shfl_down(S2p, off); }
      if (lane == 0) { s_wred[wv] = Zp; s_wred[16 + wv] = S2p; }
#pragma unroll
      for (int off = 16; off < 64; off <<= 1) {
        acc4.x += __shfl_down(acc4.x, off); acc4.y += __shfl_down(acc4.y, off);
        acc4.z += __shfl_down(acc4.z, off); acc4.w += __shfl_down(acc4.w, off);
      }
      if (lane < 16) ((float4*)s_part)[wv * 16 + lane] = acc4;
    }
    __syncthreads();
    if (tid < 64) {
      float a = 0.f;
#pragma unroll
      for (int w = 0; w < 16; ++w) a += s_part[w * 64 + tid];
      astore(P.AccP + p * 16384 + (b * 4 + chunk) * 64 + tid, a);
      s_kprev[tid] = s_key[tid];
    } else if (tid == 64) {
      float Z = 0.f, S2 = 0.f;
#pragma unroll
      for (int k = 0; k < 16; ++k) { Z += s_wred[k]; S2 += s_wred[16 + k]; }
      astore(P.ZP + p * 256 + b * 4 + chunk, Z);
      astore(P.S2P + p * 256 + b * 4 + chunk, S2);
    }
    __syncthreads();                              // drains stores before post
    if (tid == 0) __hip_atomic_fetch_add(ctr, 1u, __ATOMIC_RELEASE, SCOPE_AGT);  // post B
  }

  if (chunk == 0 && tid == 64) atomicAdd(P.out + 8388608, lossacc * (1.f / 4096.f));
}

// W2h[chunk][rp][cc] = half2{W[2rp][col], W[2rp+1][col]}, col = g*512 + chunk*128 + jl,
// cc = jl*4+g. rows [0,256)=W_ih(x), [256,768)=W_hh, [768,832)=W_ih read-rows folded (R=4).
__global__ void build_w2h(const float* __restrict__ W_ih, const float* __restrict__ W_hh,
                          unsigned* __restrict__ W2h) {
  const int id = blockIdx.x * 256 + threadIdx.x;   // over 4*416*512
  if (id >= 851968) return;
  const int chunk = id / 212992;
  const int rem   = id % 212992;
  const int rp    = rem >> 9;
  const int cc    = rem & 511;
  const int jl = cc >> 2, g = cc & 3;
  const int col = g * 512 + chunk * 128 + jl;
  float v[2];
#pragma unroll
  for (int k = 0; k < 2; ++k) {
    const int row = rp * 2 + k;
    if (row < 256)      v[k] = W_ih[(size_t)row * 2048 + col];
    else if (row < 768) v[k] = W_hh[(size_t)(row - 256) * 2048 + col];
    else {
      const float* p0 = W_ih + (size_t)(256 + (row - 768) * 4) * 2048 + col;
      v[k] = p0[0] + p0[2048] + p0[4096] + p0[6144];
    }
  }
  const __half2 h2v = __floats2half2_rn(v[0], v[1]);
  W2h[id] = *(const unsigned*)&h2v;
}

__global__ void build_wkg(const float* __restrict__ W_key, const float* __restrict__ W_gen,
                          _Float16* __restrict__ Wkg) {
  const int id = blockIdx.x * 256 + threadIdx.x;   // 512*128
  if (id >= 65536) return;
  const int row = id >> 7, cl = id & 127;
  const float v = (cl < 64) ? W_key[(size_t)row * 64 + cl] : W_gen[(size_t)row * 64 + cl - 64];
  Wkg[id] = (_Float16)v;
}

__global__ void build_wy(const float* __restrict__ W_out, _Float16* __restrict__ Wy) {
  const int id = blockIdx.x * 256 + threadIdx.x;   // 512*256
  if (id >= 131072) return;
  Wy[id] = (_Float16)W_out[id];
}

extern "C" void kernel_launch(void* const* d_in, const int* in_sizes, int n_in,
                              void* d_out, int out_size, void* d_ws, size_t ws_size,
                              hipStream_t stream) {
  const float* xs     = (const float*)d_in[0];
  const float* W_ih   = (const float*)d_in[1];
  const float* W_hh   = (const float*)d_in[2];
  const float* b_lstm = (const float*)d_in[3];
  const float* W_out  = (const float*)d_in[4];
  const float* b_out  = (const float*)d_in[5];
  const float* W_key  = (const float*)d_in[6];
  const float* b_key  = (const float*)d_in[7];
  const float* W_beta = (const float*)d_in[8];
  const float* b_beta = (const float*)d_in[9];
  const float* W_gen  = (const float*)d_in[10];
  const float* b_gen  = (const float*)d_in[11];
  float* out = (float*)d_out;

  float* ws = (float*)d_ws;
  unsigned* W2h = (unsigned*)ws;            //   851,968 u32
  _Float16* Wkg = (_Float16*)(ws + 851968); //    65,536 h (32,768 f)
  _Float16* Wy  = (_Float16*)(ws + 884736); //   131,072 h (65,536 f)
  float* hbuf  = ws     + 950272;           //  2 x 32,768
  float* keyP  = hbuf   + 65536;            //  2 x 16,384
  float* genP  = keyP   + 32768;            //  2 x 16,384
  float* yP    = genP   + 32768;            //  2 x 65,536
  float* betaP = yP     + 131072;           //  2 x 256
  float* AccP  = betaP  + 512;              //  2 x 16,384
  float* ZP    = AccP   + 32768;            //  2 x 256
  float* S2P   = ZP     + 512;              //  2 x 256
  unsigned* ctr = (unsigned*)(S2P + 512);   //  2,048 u32

  hipMemsetAsync(ctr, 0, 2048 * sizeof(unsigned), stream);
  hipMemsetAsync(out + 8388608, 0, sizeof(float), stream);

  build_w2h<<<dim3(3328), dim3(256), 0, stream>>>(W_ih, W_hh, W2h);
  build_wkg<<<dim3(256), dim3(256), 0, stream>>>(W_key, W_gen, Wkg);
  build_wy<<<dim3(512),  dim3(256), 0, stream>>>(W_out, Wy);

  P4 prm;
  prm.W2h = W2h; prm.Wkg = Wkg; prm.Wy = Wy;
  prm.b_lstm = b_lstm; prm.b_out = b_out; prm.b_key = b_key;
  prm.W_beta = W_beta; prm.b_beta = b_beta; prm.b_gen = b_gen;
  prm.xs = xs;
  prm.hbuf = hbuf; prm.keyP = keyP; prm.genP = genP; prm.yP = yP; prm.betaP = betaP;
  prm.AccP = AccP; prm.ZP = ZP; prm.S2P = S2P;
  prm.ctr = ctr;  prm.out = out;

  void* kargs[] = { &prm };
  hipLaunchCooperativeKernel(reinterpret_cast<void*>(&dnc_b4),
                             dim3(256), dim3(1024), kargs, 0, stream);
}